// Round 6
// baseline (6475.712 us; speedup 1.0000x reference)
//
#include <hip/hip_runtime.h>
#include <cstddef>
#include <cstdint>

#define S_LEN 64
#define BATCH 128
#define T_LEN 32
#define E_DIM 256
#define VOCAB 32000
#define XDIM 1792
#define MPAD 4096

typedef unsigned short bfu;
typedef short short8 __attribute__((ext_vector_type(8)));
typedef float f32x4 __attribute__((ext_vector_type(4)));

__device__ __forceinline__ float sigm(float x) { return 1.f / (1.f + expf(-x)); }
__device__ __forceinline__ bfu f2b(float f) {
    unsigned int x = __float_as_uint(f);
    x += 0x7fffu + ((x >> 16) & 1u);
    return (bfu)(x >> 16);
}
__device__ __forceinline__ float b2f(bfu u) { return __uint_as_float(((unsigned)u) << 16); }
__device__ __forceinline__ f32x4 MFMA16(short8 a, short8 b, f32x4 c) {
    return __builtin_amdgcn_mfma_f32_16x16x32_bf16(a, b, c, 0, 0, 0);
}

#define GLDS(gsrc, ldst)                                                       \
    __builtin_amdgcn_global_load_lds(                                          \
        (const __attribute__((address_space(1))) void*)(gsrc),                 \
        (__attribute__((address_space(3))) void*)(ldst), 16, 0, 0)

// ---------------------------------------------------------------- utilities
__global__ void zero_kernel(float* __restrict__ p, int n) {
    int i = blockIdx.x * 256 + threadIdx.x;
    if (i < n) p[i] = 0.f;
}

__global__ void conv_f2b(const float* __restrict__ in, bfu* __restrict__ out, int n4) {
    int i = blockIdx.x * 256 + threadIdx.x;
    if (i >= n4) return;
    float4 v = ((const float4*)in)[i];
    ushort4 o;
    o.x = f2b(v.x); o.y = f2b(v.y); o.z = f2b(v.z); o.w = f2b(v.w);
    ((ushort4*)out)[i] = o;
}

__global__ void gather_emb(const float* __restrict__ table, const int* __restrict__ idx,
                           bfu* __restrict__ out, int total) {
    int i = blockIdx.x * 256 + threadIdx.x;
    if (i >= total) return;
    int row = i >> 8, k = i & 255;
    out[i] = f2b(table[(size_t)idx[row] * E_DIM + k]);
}

__global__ void gather_trg(const float* __restrict__ table, const int* __restrict__ trg,
                           bfu* __restrict__ Xb, int total) {
    int i = blockIdx.x * 256 + threadIdx.x;
    if (i >= total) return;
    int row = i >> 8, k = i & 255;
    Xb[(size_t)row * XDIM + 1536 + k] = f2b(table[(size_t)trg[row] * E_DIM + k]);
}

// ----------------------------------------------- generic bf16 MFMA GEMM (NT)
// round-4 verified schedule: single __syncthreads per K-step.
__global__ __launch_bounds__(256) void gemm_bf16(
    const bfu* __restrict__ A0, int lda0, const bfu* __restrict__ W0, int ldw0,
    float* __restrict__ C0, int ldc0, const float* __restrict__ bias0, int K0,
    const bfu* __restrict__ A1, int lda1, const bfu* __restrict__ W1, int ldw1,
    float* __restrict__ C1, int ldc1, const float* __restrict__ bias1, int K1,
    int act, bfu* __restrict__ Cb0)
{
    const int z = blockIdx.z;
    const bfu* A = z ? A1 : A0;
    const bfu* W = z ? W1 : W0;
    float*     C = z ? C1 : C0;
    const float* bias = z ? bias1 : bias0;
    bfu*       Cb = z ? nullptr : Cb0;
    const int lda = z ? lda1 : lda0;
    const int ldw = z ? ldw1 : ldw0;
    const int ldc = z ? ldc1 : ldc0;
    const int K   = z ? K1 : K0;

    __shared__ short lds[2][2][4096];
    const int tid  = threadIdx.x;
    const int wid  = tid >> 6, lane = tid & 63;
    const int l15  = lane & 15, lk = lane >> 4;
    const int wr   = (wid >> 1) * 64, wc = (wid & 1) * 64;
    const size_t row0 = (size_t)blockIdx.y * 128;
    const size_t col0 = (size_t)blockIdx.x * 128;

    const int r0 = tid & 127, kc0 = tid >> 7;
    const int kc1 = kc0 + 2;
    const int sb0 = (wid * 64) * 16;
    const int sb1 = (wid * 64 + 256) * 16;

    f32x4 acc[4][4];
#pragma unroll
    for (int m = 0; m < 4; ++m)
#pragma unroll
        for (int n = 0; n < 4; ++n) acc[m][n] = (f32x4){0.f, 0.f, 0.f, 0.f};

    auto stage = [&](int buf, int kt) {
        char* ba = (char*)&lds[buf][0][0];
        char* bb = (char*)&lds[buf][1][0];
        GLDS(A + (row0 + r0) * (size_t)lda + kt + kc0 * 8, ba + sb0);
        GLDS(A + (row0 + r0) * (size_t)lda + kt + kc1 * 8, ba + sb1);
        GLDS(W + (col0 + r0) * (size_t)ldw + kt + kc0 * 8, bb + sb0);
        GLDS(W + (col0 + r0) * (size_t)ldw + kt + kc1 * 8, bb + sb1);
    };

    stage(0, 0);
    __syncthreads();
    const int nk = K >> 5;
    for (int t = 0; t < nk; ++t) {
        const int buf = t & 1;
        if (t + 1 < nk) stage(buf ^ 1, (t + 1) << 5);
        short8 af[4], bf_[4];
#pragma unroll
        for (int m = 0; m < 4; ++m)
            af[m] = *(const short8*)&lds[buf][0][lk * 1024 + (wr + m * 16 + l15) * 8];
#pragma unroll
        for (int n = 0; n < 4; ++n)
            bf_[n] = *(const short8*)&lds[buf][1][lk * 1024 + (wc + n * 16 + l15) * 8];
#pragma unroll
        for (int m = 0; m < 4; ++m)
#pragma unroll
            for (int n = 0; n < 4; ++n)
                acc[m][n] = MFMA16(af[m], bf_[n], acc[m][n]);
        __syncthreads();
    }

    float bv[4];
#pragma unroll
    for (int n = 0; n < 4; ++n)
        bv[n] = bias ? bias[col0 + wc + n * 16 + l15] : 0.f;
    const size_t crow = row0 + wr + lk * 4;
#pragma unroll
    for (int m = 0; m < 4; ++m) {
#pragma unroll
        for (int q = 0; q < 4; ++q) {
            const size_t r = crow + m * 16 + q;
            float* cp = C + r * ldc + col0 + wc + l15;
            bfu*   cb = Cb ? (Cb + r * ldc + col0 + wc + l15) : nullptr;
#pragma unroll
            for (int n = 0; n < 4; ++n) {
                float v = acc[m][n][q] + bv[n];
                if (act) v = tanhf(v);
                cp[n * 16] = v;
                if (Cb) cb[n * 16] = f2b(v);
            }
        }
    }
}

// ----------------------------------------------- big output GEMM, 256x256 tile
// round-4 schedule (single __syncthreads) + fused logsumexp partial epilogue.
__global__ __launch_bounds__(512) void gemm_big(
    const bfu* __restrict__ A, const bfu* __restrict__ W,
    float* __restrict__ C, const float* __restrict__ bias,
    float* __restrict__ pmax, float* __restrict__ psum)
{
    __shared__ short lds[2][2][8192];
    __shared__ float sm4[4][256];
    __shared__ float ss4[4][256];
    const int tid = threadIdx.x;
    const int wid = tid >> 6, lane = tid & 63;
    const int l15 = lane & 15, lk = lane >> 4;
    const int wr = (wid >> 2) * 128;
    const int wcc = (wid & 3) * 64;
    const int fid  = blockIdx.y * 125 + blockIdx.x;       // 2000 = 8*250
    const int fid2 = (fid & 7) * 250 + (fid >> 3);
    const int bx = fid2 / 16, by = fid2 % 16;
    const size_t row0 = (size_t)by * 256;
    const size_t col0 = (size_t)bx * 256;

    f32x4 acc[8][4];
#pragma unroll
    for (int m = 0; m < 8; ++m)
#pragma unroll
        for (int n = 0; n < 4; ++n) acc[m][n] = (f32x4){0.f, 0.f, 0.f, 0.f};

    auto stage = [&](int buf, int kt) {
        char* ba = (char*)&lds[buf][0][0];
        char* bb = (char*)&lds[buf][1][0];
#pragma unroll
        for (int it = 0; it < 2; ++it) {
            int c = it * 512 + tid;
            int kc = c >> 8, row = c & 255;
            int base = (it * 512 + wid * 64) * 16;
            GLDS(A + (row0 + row) * (size_t)XDIM + kt + kc * 8, ba + base);
            GLDS(W + (col0 + row) * (size_t)XDIM + kt + kc * 8, bb + base);
        }
    };

    stage(0, 0);
    __syncthreads();
    for (int t = 0; t < 56; ++t) {
        const int buf = t & 1;
        if (t < 55) stage(buf ^ 1, (t + 1) * 32);
        short8 af[8], bf_[4];
#pragma unroll
        for (int m = 0; m < 8; ++m)
            af[m] = *(const short8*)&lds[buf][0][lk * 2048 + (wr + m * 16 + l15) * 8];
#pragma unroll
        for (int n = 0; n < 4; ++n)
            bf_[n] = *(const short8*)&lds[buf][1][lk * 2048 + (wcc + n * 16 + l15) * 8];
#pragma unroll
        for (int m = 0; m < 8; ++m)
#pragma unroll
            for (int n = 0; n < 4; ++n)
                acc[m][n] = MFMA16(af[m], bf_[n], acc[m][n]);
        __syncthreads();
    }

    const bool rowok = (row0 + wr < 3968);   // wave-uniform M-pad guard
    float bv[4];
#pragma unroll
    for (int n = 0; n < 4; ++n) bv[n] = bias[col0 + wcc + n * 16 + l15];
#pragma unroll
    for (int m = 0; m < 8; ++m) {
#pragma unroll
        for (int q = 0; q < 4; ++q) {
            float v[4];
#pragma unroll
            for (int n = 0; n < 4; ++n) v[n] = acc[m][n][q] + bv[n];
            if (rowok) {
                const size_t r = row0 + wr + lk * 4 + m * 16 + q;
                float* cp = C + r * VOCAB + col0 + wcc + l15;
#pragma unroll
                for (int n = 0; n < 4; ++n) cp[n * 16] = v[n];
            }
            float mx = fmaxf(fmaxf(v[0], v[1]), fmaxf(v[2], v[3]));
            mx = fmaxf(mx, __shfl_xor(mx, 1));
            mx = fmaxf(mx, __shfl_xor(mx, 2));
            mx = fmaxf(mx, __shfl_xor(mx, 4));
            mx = fmaxf(mx, __shfl_xor(mx, 8));
            float se = expf(v[0] - mx) + expf(v[1] - mx) + expf(v[2] - mx) + expf(v[3] - mx);
            se += __shfl_xor(se, 1);
            se += __shfl_xor(se, 2);
            se += __shfl_xor(se, 4);
            se += __shfl_xor(se, 8);
            if (rowok && l15 == 0) {
                int rloc = (wid >> 2) * 128 + lk * 4 + m * 16 + q;
                sm4[wid & 3][rloc] = mx;
                ss4[wid & 3][rloc] = se;
            }
        }
    }
    __syncthreads();
    if (tid < 256 && row0 + tid < 3968) {
        float M = sm4[0][tid];
        M = fmaxf(M, sm4[1][tid]);
        M = fmaxf(M, sm4[2][tid]);
        M = fmaxf(M, sm4[3][tid]);
        float S = 0.f;
#pragma unroll
        for (int w = 0; w < 4; ++w) S += ss4[w][tid] * expf(sm4[w][tid] - M);
        pmax[(row0 + tid) * 125 + bx] = M;
        psum[(row0 + tid) * 125 + bx] = S;
    }
}

// ----------------------------------------------- fused encoder step (reg-only)
// grid (16 u-slices, 1, 2 dirs), 256 thr. All operands L2-resident; MFMA
// fragments loaded DIRECTLY from global to registers. No LDS, no barriers.
__global__ __launch_bounds__(256) void enc_step(
    const float* __restrict__ gi_f, const float* __restrict__ gi_b,
    const bfu* __restrict__ Whhf_b, const bfu* __restrict__ Whhb_b,
    const float* __restrict__ bhh_f, const float* __restrict__ bhh_b,
    const float* __restrict__ hin, float* __restrict__ hout,
    const bfu* __restrict__ hbin, bfu* __restrict__ hbout,
    bfu* __restrict__ encbt, int s)
{
    const int tid = threadIdx.x;
    const int wid = tid >> 6, lane = tid & 63;
    const int l15 = lane & 15, lk = lane >> 4;
    const int dir = blockIdx.z;
    const int u0 = blockIdx.x * 32;
    const int p = dir ? (S_LEN - 1 - s) : s;
    const bfu* Whh = dir ? Whhb_b : Whhf_b;
    const float* bhh = dir ? bhh_b : bhh_f;
    const float* gi = (dir ? gi_b : gi_f) + (size_t)p * BATCH * 1536;

    // per-lane fragment base pointers (K advances via immediate offsets)
    const bfu* ap0 = hbin + (size_t)(wid * 32 + l15) * 1024 + dir * 512 + lk * 8;
    const bfu* ap1 = ap0 + (size_t)16 * 1024;
    const bfu* bp0 = Whh + (size_t)(u0 + l15) * 512 + lk * 8;          // r, j=0
    const bfu* bp1 = Whh + (size_t)(u0 + 16 + l15) * 512 + lk * 8;     // r, j=1
    const bfu* bp2 = Whh + (size_t)(512 + u0 + l15) * 512 + lk * 8;    // z, j=0
    const bfu* bp3 = Whh + (size_t)(512 + u0 + 16 + l15) * 512 + lk * 8;
    const bfu* bp4 = Whh + (size_t)(1024 + u0 + l15) * 512 + lk * 8;   // n, j=0
    const bfu* bp5 = Whh + (size_t)(1024 + u0 + 16 + l15) * 512 + lk * 8;

    f32x4 acc[2][6];
#pragma unroll
    for (int m = 0; m < 2; ++m)
#pragma unroll
        for (int n = 0; n < 6; ++n) acc[m][n] = (f32x4){0.f, 0.f, 0.f, 0.f};

#pragma unroll
    for (int kk = 0; kk < 16; ++kk) {
        const int o = kk * 32;
        short8 a0 = *(const short8*)(ap0 + o);
        short8 a1 = *(const short8*)(ap1 + o);
        short8 b0 = *(const short8*)(bp0 + o);
        short8 b1 = *(const short8*)(bp1 + o);
        short8 b2 = *(const short8*)(bp2 + o);
        short8 b3 = *(const short8*)(bp3 + o);
        short8 b4 = *(const short8*)(bp4 + o);
        short8 b5 = *(const short8*)(bp5 + o);
        acc[0][0] = MFMA16(a0, b0, acc[0][0]);
        acc[1][0] = MFMA16(a1, b0, acc[1][0]);
        acc[0][1] = MFMA16(a0, b1, acc[0][1]);
        acc[1][1] = MFMA16(a1, b1, acc[1][1]);
        acc[0][2] = MFMA16(a0, b2, acc[0][2]);
        acc[1][2] = MFMA16(a1, b2, acc[1][2]);
        acc[0][3] = MFMA16(a0, b3, acc[0][3]);
        acc[1][3] = MFMA16(a1, b3, acc[1][3]);
        acc[0][4] = MFMA16(a0, b4, acc[0][4]);
        acc[1][4] = MFMA16(a1, b4, acc[1][4]);
        acc[0][5] = MFMA16(a0, b5, acc[0][5]);
        acc[1][5] = MFMA16(a1, b5, acc[1][5]);
    }

    // in-register gate
#pragma unroll
    for (int m = 0; m < 2; ++m) {
#pragma unroll
        for (int q = 0; q < 4; ++q) {
            const int b = wid * 32 + m * 16 + lk * 4 + q;
            const float* gib = gi + (size_t)b * 1536;
#pragma unroll
            for (int j = 0; j < 2; ++j) {
                const int u = u0 + j * 16 + l15;
                float rr = sigm(gib[u] + acc[m][j][q] + bhh[u]);
                float zz = sigm(gib[512 + u] + acc[m][2 + j][q] + bhh[512 + u]);
                float nn = tanhf(gib[1024 + u] + rr * (acc[m][4 + j][q] + bhh[1024 + u]));
                float h2 = (1.f - zz) * nn + zz * hin[(size_t)b * 1024 + dir * 512 + u];
                hout[(size_t)b * 1024 + dir * 512 + u] = h2;
                hbout[(size_t)b * 1024 + dir * 512 + u] = f2b(h2);
                encbt[((size_t)b * S_LEN + p) * 1024 + dir * 512 + u] = f2b(h2);
            }
        }
    }
}

// ----------------------------------------------- fused hp + attention step
__global__ __launch_bounds__(256) void attn_fused(
    const bfu* __restrict__ hb, const bfu* __restrict__ Wahb,
    const float* __restrict__ encp, const bfu* __restrict__ encbt,
    const float* __restrict__ v_attn, const int* __restrict__ src,
    bfu* __restrict__ wbuf, bfu* __restrict__ Xb, int t)
{
    __shared__ float hls[512];
    __shared__ float vas[512];
    __shared__ float hps[512];
    __shared__ float sc[64];
    const int b = blockIdx.x, tid = threadIdx.x;
    for (int i = tid; i < 512; i += 256) {
        hls[i] = b2f(hb[(size_t)b * 512 + i]);
        vas[i] = v_attn[i];
    }
    __syncthreads();
    for (int j = tid; j < 512; j += 256) {
        const uint4* wrow = (const uint4*)(Wahb + (size_t)j * 1536);
        float acc = 0.f;
#pragma unroll 8
        for (int k8 = 0; k8 < 64; ++k8) {
            uint4 wv = wrow[k8];
            const float* xp = &hls[k8 * 8];
            acc += __uint_as_float(wv.x << 16) * xp[0] + __uint_as_float(wv.x & 0xffff0000u) * xp[1]
                 + __uint_as_float(wv.y << 16) * xp[2] + __uint_as_float(wv.y & 0xffff0000u) * xp[3]
                 + __uint_as_float(wv.z << 16) * xp[4] + __uint_as_float(wv.z & 0xffff0000u) * xp[5]
                 + __uint_as_float(wv.w << 16) * xp[6] + __uint_as_float(wv.w & 0xffff0000u) * xp[7];
        }
        hps[j] = acc;
    }
    __syncthreads();
    const int s = tid >> 2, l4 = tid & 3;
    const float* ep = encp + ((size_t)b * S_LEN + s) * 512;
    float part = 0.f;
#pragma unroll 4
    for (int d = l4; d < 512; d += 4) part += vas[d] * tanhf(ep[d] + hps[d]);
    part += __shfl_xor(part, 1);
    part += __shfl_xor(part, 2);
    if (l4 == 0) sc[s] = (src[s * BATCH + b] != 0) ? part : -1e10f;
    __syncthreads();
    if (tid < 64) {
        float x = sc[tid], mx = x;
        for (int o = 1; o < 64; o <<= 1) mx = fmaxf(mx, __shfl_xor(mx, o));
        float e = expf(x - mx), s2 = e;
        for (int o = 1; o < 64; o <<= 1) s2 += __shfl_xor(s2, o);
        sc[tid] = e / s2;
    }
    __syncthreads();
    bfu* xw = Xb + ((size_t)t * BATCH + b) * XDIM + 512;
#pragma unroll
    for (int c = 0; c < 4; ++c) {
        int e = tid + 256 * c;
        float a2 = 0.f;
#pragma unroll 8
        for (int s2 = 0; s2 < S_LEN; ++s2) a2 += sc[s2] * b2f(encbt[((size_t)b * S_LEN + s2) * 1024 + e]);
        bfu v = f2b(a2);
        wbuf[(size_t)b * 1024 + e] = v;
        xw[e] = v;
    }
}

// ----------------------------------------------- fused decoder GEMM + gate (reg-only)
// grid 16 u-slices, 256 thr. acc_h = h@Whhd^T (K=512); acc_w = w@Wihd_w^T (K=1024).
// Direct global->register fragment loads; no LDS, no barriers.
__global__ __launch_bounds__(256) void dec_step_gemm(
    const float* __restrict__ gie, const bfu* __restrict__ Whhd_b,
    const bfu* __restrict__ Wihd_b, const float* __restrict__ bhh_d,
    const bfu* __restrict__ hbin, const bfu* __restrict__ wbuf,
    const float* __restrict__ hin, float* __restrict__ hout,
    bfu* __restrict__ hbout, bfu* __restrict__ Xb, int t)
{
    const int tid = threadIdx.x;
    const int wid = tid >> 6, lane = tid & 63;
    const int l15 = lane & 15, lk = lane >> 4;
    const int u0 = blockIdx.x * 32;

    f32x4 acc_h[2][6], acc_w[2][6];
#pragma unroll
    for (int m = 0; m < 2; ++m)
#pragma unroll
        for (int n = 0; n < 6; ++n) {
            acc_h[m][n] = (f32x4){0.f, 0.f, 0.f, 0.f};
            acc_w[m][n] = (f32x4){0.f, 0.f, 0.f, 0.f};
        }

    // ---- loop 1: acc_h = hbin[128x512] @ Whhd rows (K=512)
    {
        const bfu* ap0 = hbin + (size_t)(wid * 32 + l15) * 512 + lk * 8;
        const bfu* ap1 = ap0 + (size_t)16 * 512;
        const bfu* bp0 = Whhd_b + (size_t)(u0 + l15) * 512 + lk * 8;
        const bfu* bp1 = Whhd_b + (size_t)(u0 + 16 + l15) * 512 + lk * 8;
        const bfu* bp2 = Whhd_b + (size_t)(512 + u0 + l15) * 512 + lk * 8;
        const bfu* bp3 = Whhd_b + (size_t)(512 + u0 + 16 + l15) * 512 + lk * 8;
        const bfu* bp4 = Whhd_b + (size_t)(1024 + u0 + l15) * 512 + lk * 8;
        const bfu* bp5 = Whhd_b + (size_t)(1024 + u0 + 16 + l15) * 512 + lk * 8;
#pragma unroll
        for (int kk = 0; kk < 16; ++kk) {
            const int o = kk * 32;
            short8 a0 = *(const short8*)(ap0 + o);
            short8 a1 = *(const short8*)(ap1 + o);
            short8 b0 = *(const short8*)(bp0 + o);
            short8 b1 = *(const short8*)(bp1 + o);
            short8 b2 = *(const short8*)(bp2 + o);
            short8 b3 = *(const short8*)(bp3 + o);
            short8 b4 = *(const short8*)(bp4 + o);
            short8 b5 = *(const short8*)(bp5 + o);
            acc_h[0][0] = MFMA16(a0, b0, acc_h[0][0]);
            acc_h[1][0] = MFMA16(a1, b0, acc_h[1][0]);
            acc_h[0][1] = MFMA16(a0, b1, acc_h[0][1]);
            acc_h[1][1] = MFMA16(a1, b1, acc_h[1][1]);
            acc_h[0][2] = MFMA16(a0, b2, acc_h[0][2]);
            acc_h[1][2] = MFMA16(a1, b2, acc_h[1][2]);
            acc_h[0][3] = MFMA16(a0, b3, acc_h[0][3]);
            acc_h[1][3] = MFMA16(a1, b3, acc_h[1][3]);
            acc_h[0][4] = MFMA16(a0, b4, acc_h[0][4]);
            acc_h[1][4] = MFMA16(a1, b4, acc_h[1][4]);
            acc_h[0][5] = MFMA16(a0, b5, acc_h[0][5]);
            acc_h[1][5] = MFMA16(a1, b5, acc_h[1][5]);
        }
    }

    // ---- loop 2: acc_w = wbuf[128x1024] @ Wihd[:,256:1280] rows (K=1024)
    {
        const bfu* ap0 = wbuf + (size_t)(wid * 32 + l15) * 1024 + lk * 8;
        const bfu* ap1 = ap0 + (size_t)16 * 1024;
        const bfu* bp0 = Wihd_b + (size_t)(u0 + l15) * 1280 + 256 + lk * 8;
        const bfu* bp1 = Wihd_b + (size_t)(u0 + 16 + l15) * 1280 + 256 + lk * 8;
        const bfu* bp2 = Wihd_b + (size_t)(512 + u0 + l15) * 1280 + 256 + lk * 8;
        const bfu* bp3 = Wihd_b + (size_t)(512 + u0 + 16 + l15) * 1280 + 256 + lk * 8;
        const bfu* bp4 = Wihd_b + (size_t)(1024 + u0 + l15) * 1280 + 256 + lk * 8;
        const bfu* bp5 = Wihd_b + (size_t)(1024 + u0 + 16 + l15) * 1280 + 256 + lk * 8;
#pragma unroll
        for (int kk = 0; kk < 32; ++kk) {
            const int o = kk * 32;
            short8 a0 = *(const short8*)(ap0 + o);
            short8 a1 = *(const short8*)(ap1 + o);
            short8 b0 = *(const short8*)(bp0 + o);
            short8 b1 = *(const short8*)(bp1 + o);
            short8 b2 = *(const short8*)(bp2 + o);
            short8 b3 = *(const short8*)(bp3 + o);
            short8 b4 = *(const short8*)(bp4 + o);
            short8 b5 = *(const short8*)(bp5 + o);
            acc_w[0][0] = MFMA16(a0, b0, acc_w[0][0]);
            acc_w[1][0] = MFMA16(a1, b0, acc_w[1][0]);
            acc_w[0][1] = MFMA16(a0, b1, acc_w[0][1]);
            acc_w[1][1] = MFMA16(a1, b1, acc_w[1][1]);
            acc_w[0][2] = MFMA16(a0, b2, acc_w[0][2]);
            acc_w[1][2] = MFMA16(a1, b2, acc_w[1][2]);
            acc_w[0][3] = MFMA16(a0, b3, acc_w[0][3]);
            acc_w[1][3] = MFMA16(a1, b3, acc_w[1][3]);
            acc_w[0][4] = MFMA16(a0, b4, acc_w[0][4]);
            acc_w[1][4] = MFMA16(a1, b4, acc_w[1][4]);
            acc_w[0][5] = MFMA16(a0, b5, acc_w[0][5]);
            acc_w[1][5] = MFMA16(a1, b5, acc_w[1][5]);
        }
    }

    // ---- in-register gate
#pragma unroll
    for (int m = 0; m < 2; ++m) {
#pragma unroll
        for (int q = 0; q < 4; ++q) {
            const int b = wid * 32 + m * 16 + lk * 4 + q;
            const float* geb = gie + ((size_t)t * BATCH + b) * 1536;
#pragma unroll
            for (int j = 0; j < 2; ++j) {
                const int u = u0 + j * 16 + l15;
                float gH_r = acc_h[m][j][q] + bhh_d[u];
                float gH_z = acc_h[m][2 + j][q] + bhh_d[512 + u];
                float gH_n = acc_h[m][4 + j][q] + bhh_d[1024 + u];
                float rr = sigm(geb[u] + acc_w[m][j][q] + gH_r);
                float zz = sigm(geb[512 + u] + acc_w[m][2 + j][q] + gH_z);
                float nn = tanhf(geb[1024 + u] + acc_w[m][4 + j][q] + rr * gH_n);
                float h2 = (1.f - zz) * nn + zz * hin[(size_t)b * 512 + u];
                hout[(size_t)b * 512 + u] = h2;
                hbout[(size_t)b * 512 + u] = f2b(h2);
                Xb[((size_t)t * BATCH + b) * XDIM + u] = f2b(h2);
            }
        }
    }
}

// ------------------------------------------- lse combine + subtract
__global__ __launch_bounds__(64) void lse_rows(
    const float* __restrict__ pmax, const float* __restrict__ psum,
    float* __restrict__ lse)
{
    const int row = blockIdx.x, lane = threadIdx.x;
    float M = -3.4e38f, S = 0.f;
    for (int j = lane; j < 125; j += 64) {
        float m2 = pmax[(size_t)row * 125 + j], s2 = psum[(size_t)row * 125 + j];
        if (m2 > M) { S = S * expf(M - m2) + s2; M = m2; }
        else        { S += s2 * expf(m2 - M); }
    }
    for (int o = 1; o < 64; o <<= 1) {
        float m2 = __shfl_xor(M, o), s2 = __shfl_xor(S, o);
        float Mn = fmaxf(M, m2);
        S = S * expf(M - Mn) + s2 * expf(m2 - Mn);
        M = Mn;
    }
    if (lane == 0) lse[row] = M + logf(S);
}

__global__ __launch_bounds__(256) void sub_lse(float* __restrict__ out,
                                               const float* __restrict__ lse) {
    int i = blockIdx.x * 256 + threadIdx.x;       // over 3968*8000 float4
    if (i >= 3968 * 8000) return;
    float l = lse[i / 8000];
    float4 v = ((float4*)out)[i];
    v.x -= l; v.y -= l; v.z -= l; v.w -= l;
    ((float4*)out)[i] = v;
}

__global__ void fill_last(float* __restrict__ out) {
    int i = blockIdx.x * 256 + threadIdx.x;
    if (i >= BATCH * VOCAB) return;
    int v = i % VOCAB;
    out[(size_t)(T_LEN - 1) * BATCH * VOCAB + i] = (v == 2) ? 100.f : 0.f;
}

// ==================================================================== launch
extern "C" void kernel_launch(void* const* d_in, const int* in_sizes, int n_in,
                              void* d_out, int out_size, void* d_ws, size_t ws_size,
                              hipStream_t stream)
{
    const int*   src     = (const int*)d_in[0];
    const int*   trg     = (const int*)d_in[2];
    const float* emb_enc = (const float*)d_in[3];
    const float* emb_dec = (const float*)d_in[4];
    const float* Wih_f   = (const float*)d_in[5];
    const float* Whh_f   = (const float*)d_in[6];
    const float* bih_f   = (const float*)d_in[7];
    const float* bhh_f   = (const float*)d_in[8];
    const float* Wih_b   = (const float*)d_in[9];
    const float* Whh_b   = (const float*)d_in[10];
    const float* bih_b   = (const float*)d_in[11];
    const float* bhh_b   = (const float*)d_in[12];
    const float* W_fc    = (const float*)d_in[13];
    const float* b_fc    = (const float*)d_in[14];
    const float* W_attn  = (const float*)d_in[15];
    const float* b_attn  = (const float*)d_in[16];
    const float* v_attn  = (const float*)d_in[17];
    const float* Wih_d   = (const float*)d_in[18];
    const float* Whh_d   = (const float*)d_in[19];
    const float* bih_d   = (const float*)d_in[20];
    const float* bhh_d   = (const float*)d_in[21];
    const float* W_out   = (const float*)d_in[22];
    const float* b_out   = (const float*)d_in[23];
    float* out = (float*)d_out;

    char* wsb = (char*)d_ws;
    size_t off = 0;
    auto alloc = [&](size_t bytes) { void* q = wsb + off; off = (off + bytes + 255) & ~(size_t)255; return q; };
    bfu*   emb_b   = (bfu*)alloc((size_t)8192 * 256 * 2);
    bfu*   encbt_b = (bfu*)alloc((size_t)8192 * 1024 * 2);
    float* encp    = (float*)alloc((size_t)8192 * 512 * 4);
    float* gi_f    = (float*)alloc((size_t)8192 * 1536 * 4);
    float* gi_b    = (float*)alloc((size_t)8192 * 1536 * 4);
    float* gie     = (float*)alloc((size_t)3968 * 1536 * 4);
    bfu*   wbuf    = (bfu*)alloc((size_t)128 * 1024 * 2);
    float* hA      = (float*)alloc((size_t)128 * 1024 * 4);
    float* hB      = (float*)alloc((size_t)128 * 1024 * 4);
    bfu*   hbA     = (bfu*)alloc((size_t)128 * 1024 * 2);
    bfu*   hbB     = (bfu*)alloc((size_t)128 * 1024 * 2);
    float* hdA     = (float*)alloc((size_t)128 * 512 * 4);
    float* hdB     = (float*)alloc((size_t)128 * 512 * 4);
    bfu*   hdbA    = (bfu*)alloc((size_t)128 * 512 * 2);
    bfu*   hdbB    = (bfu*)alloc((size_t)128 * 512 * 2);
    bfu*   Xb      = (bfu*)alloc((size_t)MPAD * XDIM * 2);
    float* pmax    = (float*)alloc((size_t)MPAD * 125 * 4);
    float* psum    = (float*)alloc((size_t)MPAD * 125 * 4);
    float* lse     = (float*)alloc((size_t)3968 * 4);
    bfu*   Wihf_b  = (bfu*)alloc((size_t)1536 * 256 * 2);
    bfu*   Wihb_b  = (bfu*)alloc((size_t)1536 * 256 * 2);
    bfu*   Whhf_b  = (bfu*)alloc((size_t)1536 * 512 * 2);
    bfu*   Whhb_b  = (bfu*)alloc((size_t)1536 * 512 * 2);
    bfu*   Wfc_b   = (bfu*)alloc((size_t)512 * 1024 * 2);
    bfu*   Wattn_b = (bfu*)alloc((size_t)512 * 1536 * 2);
    bfu*   Wihd_b  = (bfu*)alloc((size_t)1536 * 1280 * 2);
    bfu*   Whhd_b  = (bfu*)alloc((size_t)1536 * 512 * 2);
    bfu*   Wout_b  = (bfu*)alloc((size_t)VOCAB * XDIM * 2);

    auto conv = [&](const float* in, bfu* o, size_t n) {
        conv_f2b<<<(int)((n / 4 + 255) / 256), 256, 0, stream>>>(in, o, (int)(n / 4));
    };
    conv(Wih_f, Wihf_b, 1536 * 256);
    conv(Wih_b, Wihb_b, 1536 * 256);
    conv(Whh_f, Whhf_b, 1536 * 512);
    conv(Whh_b, Whhb_b, 1536 * 512);
    conv(W_fc,  Wfc_b,  512 * 1024);
    conv(W_attn, Wattn_b, 512 * 1536);
    conv(Wih_d, Wihd_b, 1536 * 1280);
    conv(Whh_d, Whhd_b, 1536 * 512);
    conv(W_out, Wout_b, (size_t)VOCAB * XDIM);

    gather_emb<<<(8192 * 256 + 255) / 256, 256, 0, stream>>>(emb_enc, src, emb_b, 8192 * 256);
    gather_trg<<<(3968 * 256 + 255) / 256, 256, 0, stream>>>(emb_dec, trg, Xb, 3968 * 256);
    zero_kernel<<<(131072 + 255) / 256, 256, 0, stream>>>(hA, 131072);
    zero_kernel<<<(65536 + 255) / 256, 256, 0, stream>>>((float*)hbA, 65536);

    // gi for all encoder steps, both dirs
    gemm_bf16<<<dim3(12, 64, 2), 256, 0, stream>>>(
        emb_b, 256, Wihf_b, 256, gi_f, 1536, bih_f, 256,
        emb_b, 256, Wihb_b, 256, gi_b, 1536, bih_b, 256, 0, nullptr);
    // gi_e for all decoder steps
    gemm_bf16<<<dim3(12, 31, 1), 256, 0, stream>>>(
        Xb + 1536, XDIM, Wihd_b, 1280, gie, 1536, bih_d, 256,
        Xb + 1536, XDIM, Wihd_b, 1280, gie, 1536, bih_d, 256, 0, nullptr);

    // encoder: 64 fused steps, register-only MFMA
    for (int s = 0; s < S_LEN; ++s) {
        const float* hin  = (s & 1) ? hB : hA;
        float*       hout = (s & 1) ? hA : hB;
        const bfu*   hbin = (s & 1) ? hbB : hbA;
        bfu*         hbout = (s & 1) ? hbA : hbB;
        enc_step<<<dim3(16, 1, 2), 256, 0, stream>>>(
            gi_f, gi_b, Whhf_b, Whhb_b, bhh_f, bhh_b,
            hin, hout, hbin, hbout, encbt_b, s);
    }
    // hid = tanh([hf,hb] @ W_fc^T + b_fc)
    gemm_bf16<<<dim3(4, 1, 1), 256, 0, stream>>>(
        hbA, 1024, Wfc_b, 1024, hdA, 512, b_fc, 1024,
        hbA, 1024, Wfc_b, 1024, hdA, 512, b_fc, 1024, 1, hdbA);
    // enc_proj
    gemm_bf16<<<dim3(4, 64, 1), 256, 0, stream>>>(
        encbt_b, 1024, Wattn_b + 512, 1536, encp, 512, b_attn, 1024,
        encbt_b, 1024, Wattn_b + 512, 1536, encp, 512, b_attn, 1024, 0, nullptr);

    // decoder: 31 steps x 2 launches
    for (int t = 0; t < T_LEN - 1; ++t) {
        const float* hin  = (t & 1) ? hdB : hdA;
        float*       hout = (t & 1) ? hdA : hdB;
        const bfu*   hbin = (t & 1) ? hdbB : hdbA;
        bfu*         hbout = (t & 1) ? hdbA : hdbB;
        attn_fused<<<BATCH, 256, 0, stream>>>(hbin, Wattn_b, encp, encbt_b,
                                              v_attn, src, wbuf, Xb, t);
        dec_step_gemm<<<16, 256, 0, stream>>>(
            gie, Whhd_b, Wihd_b, bhh_d, hbin, wbuf, hin, hout, hbout, Xb, t);
    }

    // logits + fused lse partials, combine, subtract, last plane
    gemm_big<<<dim3(125, 16), 512, 0, stream>>>(Xb, Wout_b, out, b_out, pmax, psum);
    lse_rows<<<3968, 64, 0, stream>>>(pmax, psum, lse);
    sub_lse<<<(3968 * 8000 + 255) / 256, 256, 0, stream>>>(out, lse);
    fill_last<<<(BATCH * VOCAB + 255) / 256, 256, 0, stream>>>(out);
}

// Round 7
// 4993.394 us; speedup vs baseline: 1.2969x; 1.2969x over previous
//
#include <hip/hip_runtime.h>
#include <cstddef>
#include <cstdint>

#define S_LEN 64
#define BATCH 128
#define T_LEN 32
#define E_DIM 256
#define VOCAB 32000
#define XDIM 1792
#define MPAD 4096

typedef unsigned short bfu;
typedef short short8 __attribute__((ext_vector_type(8)));
typedef float f32x4 __attribute__((ext_vector_type(4)));

__device__ __forceinline__ float sigm(float x) { return 1.f / (1.f + expf(-x)); }
__device__ __forceinline__ bfu f2b(float f) {
    unsigned int x = __float_as_uint(f);
    x += 0x7fffu + ((x >> 16) & 1u);
    return (bfu)(x >> 16);
}
__device__ __forceinline__ float b2f(bfu u) { return __uint_as_float(((unsigned)u) << 16); }
__device__ __forceinline__ f32x4 MFMA16(short8 a, short8 b, f32x4 c) {
    return __builtin_amdgcn_mfma_f32_16x16x32_bf16(a, b, c, 0, 0, 0);
}

#define GLDS(gsrc, ldst)                                                       \
    __builtin_amdgcn_global_load_lds(                                          \
        (const __attribute__((address_space(1))) void*)(gsrc),                 \
        (__attribute__((address_space(3))) void*)(ldst), 16, 0, 0)

// ---------------------------------------------------------------- utilities
__global__ void zero_kernel(float* __restrict__ p, int n) {
    int i = blockIdx.x * 256 + threadIdx.x;
    if (i < n) p[i] = 0.f;
}

// one launch converts all 9 weight tensors f32 -> bf16 (sizes compile-time)
__global__ void conv_all(
    const float* __restrict__ s0, const float* __restrict__ s1,
    const float* __restrict__ s2, const float* __restrict__ s3,
    const float* __restrict__ s4, const float* __restrict__ s5,
    const float* __restrict__ s6, const float* __restrict__ s7,
    const float* __restrict__ s8,
    bfu* __restrict__ d0, bfu* __restrict__ d1, bfu* __restrict__ d2,
    bfu* __restrict__ d3, bfu* __restrict__ d4, bfu* __restrict__ d5,
    bfu* __restrict__ d6, bfu* __restrict__ d7, bfu* __restrict__ d8)
{
    int i = blockIdx.x * 256 + threadIdx.x;
    if (i >= 15941632) return;
    const float* s; bfu* d; int base;
    if      (i <   98304) { s = s0; d = d0; base = 0; }
    else if (i <  196608) { s = s1; d = d1; base = 98304; }
    else if (i <  393216) { s = s2; d = d2; base = 196608; }
    else if (i <  589824) { s = s3; d = d3; base = 393216; }
    else if (i <  720896) { s = s4; d = d4; base = 589824; }
    else if (i <  917504) { s = s5; d = d5; base = 720896; }
    else if (i < 1409024) { s = s6; d = d6; base = 917504; }
    else if (i < 1605632) { s = s7; d = d7; base = 1409024; }
    else                  { s = s8; d = d8; base = 1605632; }
    int j = i - base;
    float4 v = ((const float4*)s)[j];
    ushort4 o;
    o.x = f2b(v.x); o.y = f2b(v.y); o.z = f2b(v.z); o.w = f2b(v.w);
    ((ushort4*)d)[j] = o;
}

__global__ void gather_emb(const float* __restrict__ table, const int* __restrict__ idx,
                           bfu* __restrict__ out, int total) {
    int i = blockIdx.x * 256 + threadIdx.x;
    if (i >= total) return;
    int row = i >> 8, k = i & 255;
    out[i] = f2b(table[(size_t)idx[row] * E_DIM + k]);
}

__global__ void gather_trg(const float* __restrict__ table, const int* __restrict__ trg,
                           bfu* __restrict__ Xb, int total) {
    int i = blockIdx.x * 256 + threadIdx.x;
    if (i >= total) return;
    int row = i >> 8, k = i & 255;
    Xb[(size_t)row * XDIM + 1536 + k] = f2b(table[(size_t)trg[row] * E_DIM + k]);
}

// ----------------------------------------------- generic bf16 MFMA GEMM (NT)
// single __syncthreads per K-step (verified r4/r6).
__global__ __launch_bounds__(256) void gemm_bf16(
    const bfu* __restrict__ A0, int lda0, const bfu* __restrict__ W0, int ldw0,
    float* __restrict__ C0, int ldc0, const float* __restrict__ bias0, int K0,
    const bfu* __restrict__ A1, int lda1, const bfu* __restrict__ W1, int ldw1,
    float* __restrict__ C1, int ldc1, const float* __restrict__ bias1, int K1,
    int act, bfu* __restrict__ Cb0)
{
    const int z = blockIdx.z;
    const bfu* A = z ? A1 : A0;
    const bfu* W = z ? W1 : W0;
    float*     C = z ? C1 : C0;
    const float* bias = z ? bias1 : bias0;
    bfu*       Cb = z ? nullptr : Cb0;
    const int lda = z ? lda1 : lda0;
    const int ldw = z ? ldw1 : ldw0;
    const int ldc = z ? ldc1 : ldc0;
    const int K   = z ? K1 : K0;

    __shared__ short lds[2][2][4096];
    const int tid  = threadIdx.x;
    const int wid  = tid >> 6, lane = tid & 63;
    const int l15  = lane & 15, lk = lane >> 4;
    const int wr   = (wid >> 1) * 64, wc = (wid & 1) * 64;
    const size_t row0 = (size_t)blockIdx.y * 128;
    const size_t col0 = (size_t)blockIdx.x * 128;

    const int r0 = tid & 127, kc0 = tid >> 7;
    const int kc1 = kc0 + 2;
    const int sb0 = (wid * 64) * 16;
    const int sb1 = (wid * 64 + 256) * 16;

    f32x4 acc[4][4];
#pragma unroll
    for (int m = 0; m < 4; ++m)
#pragma unroll
        for (int n = 0; n < 4; ++n) acc[m][n] = (f32x4){0.f, 0.f, 0.f, 0.f};

    auto stage = [&](int buf, int kt) {
        char* ba = (char*)&lds[buf][0][0];
        char* bb = (char*)&lds[buf][1][0];
        GLDS(A + (row0 + r0) * (size_t)lda + kt + kc0 * 8, ba + sb0);
        GLDS(A + (row0 + r0) * (size_t)lda + kt + kc1 * 8, ba + sb1);
        GLDS(W + (col0 + r0) * (size_t)ldw + kt + kc0 * 8, bb + sb0);
        GLDS(W + (col0 + r0) * (size_t)ldw + kt + kc1 * 8, bb + sb1);
    };

    stage(0, 0);
    __syncthreads();
    const int nk = K >> 5;
    for (int t = 0; t < nk; ++t) {
        const int buf = t & 1;
        if (t + 1 < nk) stage(buf ^ 1, (t + 1) << 5);
        short8 af[4], bf_[4];
#pragma unroll
        for (int m = 0; m < 4; ++m)
            af[m] = *(const short8*)&lds[buf][0][lk * 1024 + (wr + m * 16 + l15) * 8];
#pragma unroll
        for (int n = 0; n < 4; ++n)
            bf_[n] = *(const short8*)&lds[buf][1][lk * 1024 + (wc + n * 16 + l15) * 8];
#pragma unroll
        for (int m = 0; m < 4; ++m)
#pragma unroll
            for (int n = 0; n < 4; ++n)
                acc[m][n] = MFMA16(af[m], bf_[n], acc[m][n]);
        __syncthreads();
    }

    float bv[4];
#pragma unroll
    for (int n = 0; n < 4; ++n)
        bv[n] = bias ? bias[col0 + wc + n * 16 + l15] : 0.f;
    const size_t crow = row0 + wr + lk * 4;
#pragma unroll
    for (int m = 0; m < 4; ++m) {
#pragma unroll
        for (int q = 0; q < 4; ++q) {
            const size_t r = crow + m * 16 + q;
            float* cp = C + r * ldc + col0 + wc + l15;
            bfu*   cb = Cb ? (Cb + r * ldc + col0 + wc + l15) : nullptr;
#pragma unroll
            for (int n = 0; n < 4; ++n) {
                float v = acc[m][n][q] + bv[n];
                if (act) v = tanhf(v);
                cp[n * 16] = v;
                if (Cb) cb[n * 16] = f2b(v);
            }
        }
    }
}

// ----------------------------------------------- big output GEMM, 256x256 tile
// r4-exact (single __syncthreads, plain epilogue) — 1035 us verified.
__global__ __launch_bounds__(512) void gemm_big(
    const bfu* __restrict__ A, const bfu* __restrict__ W,
    float* __restrict__ C, const float* __restrict__ bias)
{
    __shared__ short lds[2][2][8192];
    const int tid = threadIdx.x;
    const int wid = tid >> 6, lane = tid & 63;
    const int l15 = lane & 15, lk = lane >> 4;
    const int wr = (wid >> 2) * 128;
    const int wcc = (wid & 3) * 64;
    const int fid  = blockIdx.y * 125 + blockIdx.x;       // 2000 = 8*250
    const int fid2 = (fid & 7) * 250 + (fid >> 3);
    const int bx = fid2 / 16, by = fid2 % 16;
    const size_t row0 = (size_t)by * 256;
    const size_t col0 = (size_t)bx * 256;

    f32x4 acc[8][4];
#pragma unroll
    for (int m = 0; m < 8; ++m)
#pragma unroll
        for (int n = 0; n < 4; ++n) acc[m][n] = (f32x4){0.f, 0.f, 0.f, 0.f};

    auto stage = [&](int buf, int kt) {
        char* ba = (char*)&lds[buf][0][0];
        char* bb = (char*)&lds[buf][1][0];
#pragma unroll
        for (int it = 0; it < 2; ++it) {
            int c = it * 512 + tid;
            int kc = c >> 8, row = c & 255;
            int base = (it * 512 + wid * 64) * 16;
            GLDS(A + (row0 + row) * (size_t)XDIM + kt + kc * 8, ba + base);
            GLDS(W + (col0 + row) * (size_t)XDIM + kt + kc * 8, bb + base);
        }
    };

    stage(0, 0);
    __syncthreads();
    for (int t = 0; t < 56; ++t) {
        const int buf = t & 1;
        if (t < 55) stage(buf ^ 1, (t + 1) * 32);
        short8 af[8], bf_[4];
#pragma unroll
        for (int m = 0; m < 8; ++m)
            af[m] = *(const short8*)&lds[buf][0][lk * 2048 + (wr + m * 16 + l15) * 8];
#pragma unroll
        for (int n = 0; n < 4; ++n)
            bf_[n] = *(const short8*)&lds[buf][1][lk * 2048 + (wcc + n * 16 + l15) * 8];
#pragma unroll
        for (int m = 0; m < 8; ++m)
#pragma unroll
            for (int n = 0; n < 4; ++n)
                acc[m][n] = MFMA16(af[m], bf_[n], acc[m][n]);
        __syncthreads();
    }
    if (row0 + wr < 3968) {
        float bv[4];
#pragma unroll
        for (int n = 0; n < 4; ++n) bv[n] = bias[col0 + wcc + n * 16 + l15];
#pragma unroll
        for (int m = 0; m < 8; ++m) {
#pragma unroll
            for (int q = 0; q < 4; ++q) {
                const size_t r = row0 + wr + lk * 4 + m * 16 + q;
                float* cp = C + r * VOCAB + col0 + wcc + l15;
#pragma unroll
                for (int n = 0; n < 4; ++n) cp[n * 16] = acc[m][n][q] + bv[n];
            }
        }
    }
}

// ----------------------------------------------- fused encoder step v3
// grid (32 u-slices of 16, 1, 2 dirs) = 64 blocks, 256 thr (4 waves b-split).
// Weight slice (48 rows x 512) staged to LDS once; A fragments from global.
__global__ __launch_bounds__(256) void enc_step(
    const float* __restrict__ gi_f, const float* __restrict__ gi_b,
    const bfu* __restrict__ Whhf_b, const bfu* __restrict__ Whhb_b,
    const float* __restrict__ bhh_f, const float* __restrict__ bhh_b,
    const float* __restrict__ hin, float* __restrict__ hout,
    const bfu* __restrict__ hbin, bfu* __restrict__ hbout,
    bfu* __restrict__ encbt, int s)
{
    __shared__ short Bs[64 * 48 * 8];   // 48KB  [kc64][row48][8]
    const int tid = threadIdx.x;
    const int wid = tid >> 6, lane = tid & 63;
    const int l15 = lane & 15, lk = lane >> 4;
    const int dir = blockIdx.z;
    const int u0 = blockIdx.x * 16;
    const int p = dir ? (S_LEN - 1 - s) : s;
    const bfu* Whh = dir ? Whhb_b : Whhf_b;
    const float* bhh = dir ? bhh_b : bhh_f;
    const float* gi = (dir ? gi_b : gi_f) + (size_t)p * BATCH * 1536;

    {   // stage B: 3072 chunks of 16B; row48 r -> weight row (r>>4)*512+u0+(r&15)
        char* bb = (char*)Bs;
#pragma unroll
        for (int it = 0; it < 12; ++it) {
            int c = it * 256 + tid;
            int r48 = c % 48, kc = c / 48;
            int wr = (r48 >> 4) * 512 + u0 + (r48 & 15);
            GLDS(Whh + (size_t)wr * 512 + kc * 8, bb + (it * 256 + wid * 64) * 16);
        }
    }
    __syncthreads();

    const bfu* ap0 = hbin + (size_t)(wid * 32 + l15) * 1024 + dir * 512 + lk * 8;
    const bfu* ap1 = ap0 + (size_t)16 * 1024;
    f32x4 acc[2][3];
#pragma unroll
    for (int m = 0; m < 2; ++m)
#pragma unroll
        for (int g = 0; g < 3; ++g) acc[m][g] = (f32x4){0.f, 0.f, 0.f, 0.f};

#pragma unroll
    for (int kk = 0; kk < 16; ++kk) {
        short8 a0 = *(const short8*)(ap0 + kk * 32);
        short8 a1 = *(const short8*)(ap1 + kk * 32);
#pragma unroll
        for (int g = 0; g < 3; ++g) {
            short8 bf_ = *(const short8*)&Bs[((kk * 4 + lk) * 48 + g * 16 + l15) * 8];
            acc[0][g] = MFMA16(a0, bf_, acc[0][g]);
            acc[1][g] = MFMA16(a1, bf_, acc[1][g]);
        }
    }

    const int u = u0 + l15;
    const float bR = bhh[u], bZ = bhh[512 + u], bN = bhh[1024 + u];
#pragma unroll
    for (int m = 0; m < 2; ++m) {
#pragma unroll
        for (int q = 0; q < 4; ++q) {
            const int b = wid * 32 + m * 16 + lk * 4 + q;
            const float* gib = gi + (size_t)b * 1536;
            float rr = sigm(gib[u] + acc[m][0][q] + bR);
            float zz = sigm(gib[512 + u] + acc[m][1][q] + bZ);
            float nn = tanhf(gib[1024 + u] + rr * (acc[m][2][q] + bN));
            float h2 = (1.f - zz) * nn + zz * hin[(size_t)b * 1024 + dir * 512 + u];
            hout[(size_t)b * 1024 + dir * 512 + u] = h2;
            hbout[(size_t)b * 1024 + dir * 512 + u] = f2b(h2);
            encbt[((size_t)b * S_LEN + p) * 1024 + dir * 512 + u] = f2b(h2);
        }
    }
}

// ----------------------------------------------- fused hp + attention step
__global__ __launch_bounds__(256) void attn_fused(
    const bfu* __restrict__ hb, const bfu* __restrict__ Wahb,
    const float* __restrict__ encp, const bfu* __restrict__ encbt,
    const float* __restrict__ v_attn, const int* __restrict__ src,
    bfu* __restrict__ wbuf, bfu* __restrict__ Xb, int t)
{
    __shared__ float hls[512];
    __shared__ float vas[512];
    __shared__ float hps[512];
    __shared__ float sc[64];
    const int b = blockIdx.x, tid = threadIdx.x;
    for (int i = tid; i < 512; i += 256) {
        hls[i] = b2f(hb[(size_t)b * 512 + i]);
        vas[i] = v_attn[i];
    }
    __syncthreads();
    for (int j = tid; j < 512; j += 256) {
        const uint4* wrow = (const uint4*)(Wahb + (size_t)j * 1536);
        float acc = 0.f;
#pragma unroll 8
        for (int k8 = 0; k8 < 64; ++k8) {
            uint4 wv = wrow[k8];
            const float* xp = &hls[k8 * 8];
            acc += __uint_as_float(wv.x << 16) * xp[0] + __uint_as_float(wv.x & 0xffff0000u) * xp[1]
                 + __uint_as_float(wv.y << 16) * xp[2] + __uint_as_float(wv.y & 0xffff0000u) * xp[3]
                 + __uint_as_float(wv.z << 16) * xp[4] + __uint_as_float(wv.z & 0xffff0000u) * xp[5]
                 + __uint_as_float(wv.w << 16) * xp[6] + __uint_as_float(wv.w & 0xffff0000u) * xp[7];
        }
        hps[j] = acc;
    }
    __syncthreads();
    const int s = tid >> 2, l4 = tid & 3;
    const float* ep = encp + ((size_t)b * S_LEN + s) * 512;
    float part = 0.f;
#pragma unroll 4
    for (int d = l4; d < 512; d += 4) part += vas[d] * tanhf(ep[d] + hps[d]);
    part += __shfl_xor(part, 1);
    part += __shfl_xor(part, 2);
    if (l4 == 0) sc[s] = (src[s * BATCH + b] != 0) ? part : -1e10f;
    __syncthreads();
    if (tid < 64) {
        float x = sc[tid], mx = x;
        for (int o = 1; o < 64; o <<= 1) mx = fmaxf(mx, __shfl_xor(mx, o));
        float e = expf(x - mx), s2 = e;
        for (int o = 1; o < 64; o <<= 1) s2 += __shfl_xor(s2, o);
        sc[tid] = e / s2;
    }
    __syncthreads();
    bfu* xw = Xb + ((size_t)t * BATCH + b) * XDIM + 512;
#pragma unroll
    for (int c = 0; c < 4; ++c) {
        int e = tid + 256 * c;
        float a2 = 0.f;
#pragma unroll 8
        for (int s2 = 0; s2 < S_LEN; ++s2) a2 += sc[s2] * b2f(encbt[((size_t)b * S_LEN + s2) * 1024 + e]);
        bfu v = f2b(a2);
        wbuf[(size_t)b * 1024 + e] = v;
        xw[e] = v;
    }
}

// ----------------------------------------------- fused decoder GEMM + gate v3
// grid 32 blocks (u-slice 16), 256 thr (4 waves b-split).
// Whhd slice LDS-staged; Wihd_w fragments global (wave-shared -> L1 dedup).
__global__ __launch_bounds__(256) void dec_step(
    const float* __restrict__ gie, const bfu* __restrict__ Whhd_b,
    const bfu* __restrict__ Wihd_b, const float* __restrict__ bhh_d,
    const bfu* __restrict__ hbin, const bfu* __restrict__ wbuf,
    const float* __restrict__ hin, float* __restrict__ hout,
    bfu* __restrict__ hbout, bfu* __restrict__ Xb, int t)
{
    __shared__ short Bs[64 * 48 * 8];   // 48KB Whhd slice
    const int tid = threadIdx.x;
    const int wid = tid >> 6, lane = tid & 63;
    const int l15 = lane & 15, lk = lane >> 4;
    const int u0 = blockIdx.x * 16;

    {
        char* bb = (char*)Bs;
#pragma unroll
        for (int it = 0; it < 12; ++it) {
            int c = it * 256 + tid;
            int r48 = c % 48, kc = c / 48;
            int wr = (r48 >> 4) * 512 + u0 + (r48 & 15);
            GLDS(Whhd_b + (size_t)wr * 512 + kc * 8, bb + (it * 256 + wid * 64) * 16);
        }
    }
    __syncthreads();

    f32x4 accR[2], accZ[2], accNH[2], accNW[2];
#pragma unroll
    for (int m = 0; m < 2; ++m) {
        accR[m] = (f32x4){0.f, 0.f, 0.f, 0.f};
        accZ[m] = (f32x4){0.f, 0.f, 0.f, 0.f};
        accNH[m] = (f32x4){0.f, 0.f, 0.f, 0.f};
        accNW[m] = (f32x4){0.f, 0.f, 0.f, 0.f};
    }

    // loop1: h-side (K=512), B from LDS
    {
        const bfu* ap0 = hbin + (size_t)(wid * 32 + l15) * 512 + lk * 8;
        const bfu* ap1 = ap0 + (size_t)16 * 512;
#pragma unroll
        for (int kk = 0; kk < 16; ++kk) {
            short8 a0 = *(const short8*)(ap0 + kk * 32);
            short8 a1 = *(const short8*)(ap1 + kk * 32);
            short8 br = *(const short8*)&Bs[((kk * 4 + lk) * 48 + l15) * 8];
            short8 bz = *(const short8*)&Bs[((kk * 4 + lk) * 48 + 16 + l15) * 8];
            short8 bn = *(const short8*)&Bs[((kk * 4 + lk) * 48 + 32 + l15) * 8];
            accR[0] = MFMA16(a0, br, accR[0]);
            accR[1] = MFMA16(a1, br, accR[1]);
            accZ[0] = MFMA16(a0, bz, accZ[0]);
            accZ[1] = MFMA16(a1, bz, accZ[1]);
            accNH[0] = MFMA16(a0, bn, accNH[0]);
            accNH[1] = MFMA16(a1, bn, accNH[1]);
        }
    }
    // loop2: w-side (K=1024), B global (shared across waves)
    {
        const bfu* ap0 = wbuf + (size_t)(wid * 32 + l15) * 1024 + lk * 8;
        const bfu* ap1 = ap0 + (size_t)16 * 1024;
        const bfu* bpr = Wihd_b + (size_t)(u0 + l15) * 1280 + 256 + lk * 8;
        const bfu* bpz = Wihd_b + (size_t)(512 + u0 + l15) * 1280 + 256 + lk * 8;
        const bfu* bpn = Wihd_b + (size_t)(1024 + u0 + l15) * 1280 + 256 + lk * 8;
#pragma unroll
        for (int kk = 0; kk < 32; ++kk) {
            short8 a0 = *(const short8*)(ap0 + kk * 32);
            short8 a1 = *(const short8*)(ap1 + kk * 32);
            short8 br = *(const short8*)(bpr + kk * 32);
            short8 bz = *(const short8*)(bpz + kk * 32);
            short8 bn = *(const short8*)(bpn + kk * 32);
            accR[0] = MFMA16(a0, br, accR[0]);
            accR[1] = MFMA16(a1, br, accR[1]);
            accZ[0] = MFMA16(a0, bz, accZ[0]);
            accZ[1] = MFMA16(a1, bz, accZ[1]);
            accNW[0] = MFMA16(a0, bn, accNW[0]);
            accNW[1] = MFMA16(a1, bn, accNW[1]);
        }
    }

    const int u = u0 + l15;
    const float bR = bhh_d[u], bZ = bhh_d[512 + u], bN = bhh_d[1024 + u];
#pragma unroll
    for (int m = 0; m < 2; ++m) {
#pragma unroll
        for (int q = 0; q < 4; ++q) {
            const int b = wid * 32 + m * 16 + lk * 4 + q;
            const float* geb = gie + ((size_t)t * BATCH + b) * 1536;
            float rr = sigm(geb[u] + accR[m][q] + bR);
            float zz = sigm(geb[512 + u] + accZ[m][q] + bZ);
            float nn = tanhf(geb[1024 + u] + accNW[m][q] + rr * (accNH[m][q] + bN));
            float h2 = (1.f - zz) * nn + zz * hin[(size_t)b * 512 + u];
            hout[(size_t)b * 512 + u] = h2;
            hbout[(size_t)b * 512 + u] = f2b(h2);
            Xb[((size_t)t * BATCH + b) * XDIM + u] = f2b(h2);
        }
    }
}

// ------------------------------------------- in-place log-softmax (V=32000)
__global__ __launch_bounds__(256) void log_softmax_rows(float* __restrict__ data) {
    __shared__ float sm[256], ss[256];
    const size_t row = blockIdx.x;
    float* p = data + row * VOCAB;
    float4* p4 = (float4*)p;
    const int tid = threadIdx.x;
    float m = -3.4e38f, ssum = 0.f;
    for (int i = tid; i < 8000; i += 256) {
        float4 v = p4[i];
        float mx = fmaxf(fmaxf(v.x, v.y), fmaxf(v.z, v.w));
        float mn = fmaxf(m, mx);
        ssum = ssum * expf(m - mn) + expf(v.x - mn) + expf(v.y - mn)
             + expf(v.z - mn) + expf(v.w - mn);
        m = mn;
    }
    sm[tid] = m; ss[tid] = ssum;
    __syncthreads();
    for (int off = 128; off > 0; off >>= 1) {
        if (tid < off) {
            float m2 = sm[tid + off], s2 = ss[tid + off];
            float M = fmaxf(sm[tid], m2);
            ss[tid] = ss[tid] * expf(sm[tid] - M) + s2 * expf(m2 - M);
            sm[tid] = M;
        }
        __syncthreads();
    }
    const float lse = sm[0] + logf(ss[0]);
    for (int i = tid; i < 8000; i += 256) {
        float4 v = p4[i];
        v.x -= lse; v.y -= lse; v.z -= lse; v.w -= lse;
        p4[i] = v;
    }
}

__global__ void fill_last(float* __restrict__ out) {
    int i = blockIdx.x * 256 + threadIdx.x;
    if (i >= BATCH * VOCAB) return;
    int v = i % VOCAB;
    out[(size_t)(T_LEN - 1) * BATCH * VOCAB + i] = (v == 2) ? 100.f : 0.f;
}

// ==================================================================== launch
extern "C" void kernel_launch(void* const* d_in, const int* in_sizes, int n_in,
                              void* d_out, int out_size, void* d_ws, size_t ws_size,
                              hipStream_t stream)
{
    const int*   src     = (const int*)d_in[0];
    const int*   trg     = (const int*)d_in[2];
    const float* emb_enc = (const float*)d_in[3];
    const float* emb_dec = (const float*)d_in[4];
    const float* Wih_f   = (const float*)d_in[5];
    const float* Whh_f   = (const float*)d_in[6];
    const float* bih_f   = (const float*)d_in[7];
    const float* bhh_f   = (const float*)d_in[8];
    const float* Wih_b   = (const float*)d_in[9];
    const float* Whh_b   = (const float*)d_in[10];
    const float* bih_b   = (const float*)d_in[11];
    const float* bhh_b   = (const float*)d_in[12];
    const float* W_fc    = (const float*)d_in[13];
    const float* b_fc    = (const float*)d_in[14];
    const float* W_attn  = (const float*)d_in[15];
    const float* b_attn  = (const float*)d_in[16];
    const float* v_attn  = (const float*)d_in[17];
    const float* Wih_d   = (const float*)d_in[18];
    const float* Whh_d   = (const float*)d_in[19];
    const float* bih_d   = (const float*)d_in[20];
    const float* bhh_d   = (const float*)d_in[21];
    const float* W_out   = (const float*)d_in[22];
    const float* b_out   = (const float*)d_in[23];
    float* out = (float*)d_out;

    char* wsb = (char*)d_ws;
    size_t off = 0;
    auto alloc = [&](size_t bytes) { void* q = wsb + off; off = (off + bytes + 255) & ~(size_t)255; return q; };
    bfu*   emb_b   = (bfu*)alloc((size_t)8192 * 256 * 2);
    bfu*   encbt_b = (bfu*)alloc((size_t)8192 * 1024 * 2);
    float* encp    = (float*)alloc((size_t)8192 * 512 * 4);
    float* gi_f    = (float*)alloc((size_t)8192 * 1536 * 4);
    float* gi_b    = (float*)alloc((size_t)8192 * 1536 * 4);
    float* gie     = (float*)alloc((size_t)3968 * 1536 * 4);
    bfu*   wbuf    = (bfu*)alloc((size_t)128 * 1024 * 2);
    float* hA      = (float*)alloc((size_t)128 * 1024 * 4);
    float* hB      = (float*)alloc((size_t)128 * 1024 * 4);
    bfu*   hbA     = (bfu*)alloc((size_t)128 * 1024 * 2);
    bfu*   hbB     = (bfu*)alloc((size_t)128 * 1024 * 2);
    float* hdA     = (float*)alloc((size_t)128 * 512 * 4);
    float* hdB     = (float*)alloc((size_t)128 * 512 * 4);
    bfu*   hdbA    = (bfu*)alloc((size_t)128 * 512 * 2);
    bfu*   hdbB    = (bfu*)alloc((size_t)128 * 512 * 2);
    bfu*   Xb      = (bfu*)alloc((size_t)MPAD * XDIM * 2);
    bfu*   Wihf_b  = (bfu*)alloc((size_t)1536 * 256 * 2);
    bfu*   Wihb_b  = (bfu*)alloc((size_t)1536 * 256 * 2);
    bfu*   Whhf_b  = (bfu*)alloc((size_t)1536 * 512 * 2);
    bfu*   Whhb_b  = (bfu*)alloc((size_t)1536 * 512 * 2);
    bfu*   Wfc_b   = (bfu*)alloc((size_t)512 * 1024 * 2);
    bfu*   Wattn_b = (bfu*)alloc((size_t)512 * 1536 * 2);
    bfu*   Wihd_b  = (bfu*)alloc((size_t)1536 * 1280 * 2);
    bfu*   Whhd_b  = (bfu*)alloc((size_t)1536 * 512 * 2);
    bfu*   Wout_b  = (bfu*)alloc((size_t)VOCAB * XDIM * 2);

    // all weight conversions in one launch
    conv_all<<<(15941632 + 255) / 256, 256, 0, stream>>>(
        Wih_f, Wih_b, Whh_f, Whh_b, W_fc, W_attn, Wih_d, Whh_d, W_out,
        Wihf_b, Wihb_b, Whhf_b, Whhb_b, Wfc_b, Wattn_b, Wihd_b, Whhd_b, Wout_b);

    gather_emb<<<(8192 * 256 + 255) / 256, 256, 0, stream>>>(emb_enc, src, emb_b, 8192 * 256);
    gather_trg<<<(3968 * 256 + 255) / 256, 256, 0, stream>>>(emb_dec, trg, Xb, 3968 * 256);
    zero_kernel<<<(131072 + 255) / 256, 256, 0, stream>>>(hA, 131072);
    zero_kernel<<<(65536 + 255) / 256, 256, 0, stream>>>((float*)hbA, 65536);

    // gi for all encoder steps, both dirs
    gemm_bf16<<<dim3(12, 64, 2), 256, 0, stream>>>(
        emb_b, 256, Wihf_b, 256, gi_f, 1536, bih_f, 256,
        emb_b, 256, Wihb_b, 256, gi_b, 1536, bih_b, 256, 0, nullptr);
    // gi_e for all decoder steps
    gemm_bf16<<<dim3(12, 31, 1), 256, 0, stream>>>(
        Xb + 1536, XDIM, Wihd_b, 1280, gie, 1536, bih_d, 256,
        Xb + 1536, XDIM, Wihd_b, 1280, gie, 1536, bih_d, 256, 0, nullptr);

    // encoder: 64 fused steps, weight-slice in LDS, b-split waves
    for (int s = 0; s < S_LEN; ++s) {
        const float* hin  = (s & 1) ? hB : hA;
        float*       hout = (s & 1) ? hA : hB;
        const bfu*   hbin = (s & 1) ? hbB : hbA;
        bfu*         hbout = (s & 1) ? hbA : hbB;
        enc_step<<<dim3(32, 1, 2), 256, 0, stream>>>(
            gi_f, gi_b, Whhf_b, Whhb_b, bhh_f, bhh_b,
            hin, hout, hbin, hbout, encbt_b, s);
    }
    // hid = tanh([hf,hb] @ W_fc^T + b_fc)   (final enc h in hA/hbA)
    gemm_bf16<<<dim3(4, 1, 1), 256, 0, stream>>>(
        hbA, 1024, Wfc_b, 1024, hdA, 512, b_fc, 1024,
        hbA, 1024, Wfc_b, 1024, hdA, 512, b_fc, 1024, 1, hdbA);
    // enc_proj
    gemm_bf16<<<dim3(4, 64, 1), 256, 0, stream>>>(
        encbt_b, 1024, Wattn_b + 512, 1536, encp, 512, b_attn, 1024,
        encbt_b, 1024, Wattn_b + 512, 1536, encp, 512, b_attn, 1024, 0, nullptr);

    // decoder: 31 steps x 2 launches
    for (int t = 0; t < T_LEN - 1; ++t) {
        const float* hin  = (t & 1) ? hdB : hdA;
        float*       hout = (t & 1) ? hdA : hdB;
        const bfu*   hbin = (t & 1) ? hdbB : hdbA;
        bfu*         hbout = (t & 1) ? hdbA : hdbB;
        attn_fused<<<BATCH, 256, 0, stream>>>(hbin, Wattn_b, encp, encbt_b,
                                              v_attn, src, wbuf, Xb, t);
        dec_step<<<32, 256, 0, stream>>>(
            gie, Whhd_b, Wihd_b, bhh_d, hbin, wbuf, hin, hout, hbout, Xb, t);
    }

    // logits + log-softmax + last plane
    gemm_big<<<dim3(125, 16), 512, 0, stream>>>(Xb, Wout_b, out, b_out);
    log_softmax_rows<<<3968, 256, 0, stream>>>(out);
    fill_last<<<(BATCH * VOCAB + 255) / 256, 256, 0, stream>>>(out);
}